// Round 9
// baseline (311.965 us; speedup 1.0000x reference)
//
#include <hip/hip_runtime.h>

// SelfAttention: B=8, S=2048, D=1024, fp32 in/out — ALL-FP16 MFMA pipeline.
// 256x256-tile 8-wave BK=64 double-buffered MFMA core; swizzled LDS
// (pre-swizzled global staging), DEEP staging (all 8 gloads of tile t+1
// burst-issued at phase 0 of tile t => >= 1 tile-wall of latency cover),
// counted vmcnt(2)/(8), setprio, XCD-chunked block swizzle.
// Merged projection kernel (uniform NT=16): q,k = emb@W^T; vT = Wv@emb^T.
// scores: raw s/32 stored fp16; softmax adds mask/32 (fp32 math), writes fp16
// probs in place; PV fp16 MFMA, fp32 out.
// d_ws (u16): scH[32M] | emb16[16M] | B3[3M] | q16[16M] k16[16M] vT[16M]
//   = 83M u16 = 166MB.

#define B_SZ 8
#define SEQ  2048
#define DIM  1024
#define MROWS (B_SZ * SEQ)  // 16384

typedef unsigned short u16;
typedef short short8 __attribute__((ext_vector_type(8)));
typedef unsigned short u16x4 __attribute__((ext_vector_type(4)));
typedef float f32x4 __attribute__((ext_vector_type(4)));

__device__ __forceinline__ u16 f2h(float x) {
  _Float16 h = (_Float16)x;  // v_cvt_f16_f32, RNE
  union { _Float16 f; u16 u; } c; c.f = h; return c.u;
}
__device__ __forceinline__ float h2f(u16 u) {
  union { _Float16 f; u16 u; } c; c.u = u; return (float)c.f;
}

// XCD-chunked bijective swizzle (nwg % 8 == 0)
__device__ __forceinline__ int xcd_swz(int x, int nwg) {
  return (x & 7) * (nwg >> 3) + (x >> 3);
}

__device__ __forceinline__ void gload_lds16(const u16* g, u16* l) {
  __builtin_amdgcn_global_load_lds(
      (__attribute__((address_space(1))) void*)(g),
      (__attribute__((address_space(3))) void*)(l), 16, 0, 0);
}

__device__ __forceinline__ f32x4 mfma_f16(short8 a, short8 b, f32x4 c) {
  asm("v_mfma_f32_16x16x32_f16 %0, %1, %2, %0" : "+v"(c) : "v"(a), "v"(b));
  return c;
}

// ================= 256x256 8-wave GEMM core (fp16) =================
// Staging for tile t+1: ALL 8 gloads issued at phase 0 of tile t, order
// B0,B1,B2,B3,A0,A2,A1,A3. Consumption in tile t: ph0/1 need B*,A0(wm0)/A2(wm1);
// ph2/3 need A1(wm0)/A3(wm1). Waits: entry vmcnt(2) (allow A1,A3 of current
// tile), mid vmcnt(8) when prefetching (allow the 8 next-tile loads) else 0.
__device__ __forceinline__ void gemm256_core(const u16* __restrict__ Ag,
                                             const u16* __restrict__ Bg,
                                             int NT, size_t lda, size_t ldb,
                                             u16* sm, f32x4 (&acc)[8][4]) {
  const int tid = threadIdx.x;
  const int lane = tid & 63;
  const int wid = tid >> 6;   // 0..7
  const int wm = wid >> 2;    // 0..1
  const int wn = wid & 3;     // 0..3
  const int wm8 = wm << 3;
  const int wn4 = wn << 2;

  u16* sA = sm;            // [2][16384] u16 (32KB per buf)
  u16* sB = sm + 32768;

  const int bb = (lane << 4) ^ (((lane >> 5) & 1) << 5);
  const int rins = bb >> 6;
  const int cins = (bb & 63) >> 1;
  const int s0 = wid, s1 = 8 + wid, s2 = 16 + wid, s3 = 24 + wid;
  const size_t aoff0 = (size_t)((s0 >> 1) * 16 + rins) * lda + ((s0 & 1) * 32 + cins);
  const size_t aoff1 = (size_t)((s1 >> 1) * 16 + rins) * lda + ((s1 & 1) * 32 + cins);
  const size_t aoff2 = (size_t)((s2 >> 1) * 16 + rins) * lda + ((s2 & 1) * 32 + cins);
  const size_t aoff3 = (size_t)((s3 >> 1) * 16 + rins) * lda + ((s3 & 1) * 32 + cins);
  const size_t boff0 = (size_t)((s0 >> 1) * 16 + rins) * ldb + ((s0 & 1) * 32 + cins);
  const size_t boff1 = (size_t)((s1 >> 1) * 16 + rins) * ldb + ((s1 & 1) * 32 + cins);
  const size_t boff2 = (size_t)((s2 >> 1) * 16 + rins) * ldb + ((s2 & 1) * 32 + cins);
  const size_t boff3 = (size_t)((s3 >> 1) * 16 + rins) * ldb + ((s3 & 1) * 32 + cins);
  const int wid512 = wid << 9;

  const int lof = ((lane & 15) << 6) + ((lane >> 4) << 4);
  const int loe = (lof ^ (((lane >> 3) & 1) << 5)) >> 1;

#define ISSUE_A(j, nb, kt) \
  gload_lds16(Ag + aoff##j + (size_t)(kt) * 64, sA + (nb) * 16384 + (j) * 4096 + wid512)
#define ISSUE_B(j, nb, kt) \
  gload_lds16(Bg + boff##j + (size_t)(kt) * 64, sB + (nb) * 16384 + (j) * 4096 + wid512)

  // prologue: stage tile 0 into buf 0 (same order as steady state)
  ISSUE_B(0, 0, 0); ISSUE_B(1, 0, 0); ISSUE_B(2, 0, 0); ISSUE_B(3, 0, 0);
  ISSUE_A(0, 0, 0); ISSUE_A(2, 0, 0); ISSUE_A(1, 0, 0); ISSUE_A(3, 0, 0);

  int buf = 0;
  for (int kt = 0; kt < NT; ++kt) {
    const int nk = kt + 1;
    const bool pre = nk < NT;
    const int nb = buf ^ 1;
    // entry: B0-3, A0, A2 of tile kt must be in LDS; A1,A3 may still fly
    asm volatile("s_waitcnt vmcnt(2)" ::: "memory");
    __builtin_amdgcn_s_barrier();
    asm volatile("" ::: "memory");
    const u16* bufA = sA + buf * 16384;
    const u16* bufB = sB + buf * 16384;
    short8 bf[4][2];
#pragma unroll
    for (int n = 0; n < 4; ++n) {
      bf[n][0] = *(const short8*)(bufB + (wn4 + n) * 1024 + loe);
      bf[n][1] = *(const short8*)(bufB + (wn4 + n) * 1024 + 512 + loe);
    }
    // ---- phase 0 (m0,m1) + burst-issue ALL staging for tile kt+1
    {
      short8 af[2][2];
#pragma unroll
      for (int m = 0; m < 2; ++m) {
        af[m][0] = *(const short8*)(bufA + (wm8 + m) * 1024 + loe);
        af[m][1] = *(const short8*)(bufA + (wm8 + m) * 1024 + 512 + loe);
      }
      if (pre) {
        ISSUE_B(0, nb, nk); ISSUE_B(1, nb, nk); ISSUE_B(2, nb, nk); ISSUE_B(3, nb, nk);
        ISSUE_A(0, nb, nk); ISSUE_A(2, nb, nk); ISSUE_A(1, nb, nk); ISSUE_A(3, nb, nk);
      }
      __builtin_amdgcn_s_setprio(1);
#pragma unroll
      for (int m = 0; m < 2; ++m)
#pragma unroll
        for (int n = 0; n < 4; ++n) {
          acc[m][n] = mfma_f16(af[m][0], bf[n][0], acc[m][n]);
          acc[m][n] = mfma_f16(af[m][1], bf[n][1], acc[m][n]);
        }
      __builtin_amdgcn_s_setprio(0);
    }
    // ---- phase 1 (m2,m3)
    {
      short8 af[2][2];
#pragma unroll
      for (int m = 0; m < 2; ++m) {
        af[m][0] = *(const short8*)(bufA + (wm8 + 2 + m) * 1024 + loe);
        af[m][1] = *(const short8*)(bufA + (wm8 + 2 + m) * 1024 + 512 + loe);
      }
      __builtin_amdgcn_s_setprio(1);
#pragma unroll
      for (int m = 0; m < 2; ++m)
#pragma unroll
        for (int n = 0; n < 4; ++n) {
          acc[2 + m][n] = mfma_f16(af[m][0], bf[n][0], acc[2 + m][n]);
          acc[2 + m][n] = mfma_f16(af[m][1], bf[n][1], acc[2 + m][n]);
        }
      __builtin_amdgcn_s_setprio(0);
    }
    // ---- mid-tile: A1,A3 of tile kt must land (consumed by ph2/3)
    if (pre) {
      asm volatile("s_waitcnt vmcnt(8)" ::: "memory");
    } else {
      asm volatile("s_waitcnt vmcnt(0)" ::: "memory");
    }
    __builtin_amdgcn_s_barrier();
    asm volatile("" ::: "memory");
    // ---- phase 2 (m4,m5)
    {
      short8 af[2][2];
#pragma unroll
      for (int m = 0; m < 2; ++m) {
        af[m][0] = *(const short8*)(bufA + (wm8 + 4 + m) * 1024 + loe);
        af[m][1] = *(const short8*)(bufA + (wm8 + 4 + m) * 1024 + 512 + loe);
      }
      __builtin_amdgcn_s_setprio(1);
#pragma unroll
      for (int m = 0; m < 2; ++m)
#pragma unroll
        for (int n = 0; n < 4; ++n) {
          acc[4 + m][n] = mfma_f16(af[m][0], bf[n][0], acc[4 + m][n]);
          acc[4 + m][n] = mfma_f16(af[m][1], bf[n][1], acc[4 + m][n]);
        }
      __builtin_amdgcn_s_setprio(0);
    }
    // ---- phase 3 (m6,m7)
    {
      short8 af[2][2];
#pragma unroll
      for (int m = 0; m < 2; ++m) {
        af[m][0] = *(const short8*)(bufA + (wm8 + 6 + m) * 1024 + loe);
        af[m][1] = *(const short8*)(bufA + (wm8 + 6 + m) * 1024 + 512 + loe);
      }
      __builtin_amdgcn_s_setprio(1);
#pragma unroll
      for (int m = 0; m < 2; ++m)
#pragma unroll
        for (int n = 0; n < 4; ++n) {
          acc[6 + m][n] = mfma_f16(af[m][0], bf[n][0], acc[6 + m][n]);
          acc[6 + m][n] = mfma_f16(af[m][1], bf[n][1], acc[6 + m][n]);
        }
      __builtin_amdgcn_s_setprio(0);
    }
    buf ^= 1;
  }
  asm volatile("s_nop 7\n\ts_nop 7\n\ts_nop 7" ::);  // MFMA->VALU hazard guard
#undef ISSUE_A
#undef ISSUE_B
}

// ---- fp32 -> fp16 convert (vectorized)
__global__ __launch_bounds__(256) void cvt_kernel(const float* __restrict__ in,
                                                  u16* __restrict__ out, int n4) {
  int i = blockIdx.x * 256 + threadIdx.x;
  if (i >= n4) return;
  float4 v = ((const float4*)in)[i];
  u16x4 o;
  o[0] = f2h(v.x); o[1] = f2h(v.y); o[2] = f2h(v.z); o[3] = f2h(v.w);
  ((u16x4*)out)[i] = o;
}

// ---- all three weights in one launch (grid 3072; 1024 blocks per matrix)
__global__ __launch_bounds__(256) void cvt_w3_kernel(const float* __restrict__ Wq,
                                                     const float* __restrict__ Wk,
                                                     const float* __restrict__ Wv,
                                                     u16* __restrict__ B3) {
  int b = blockIdx.x;
  int w = b >> 10;                          // 0,1,2
  int i = (b & 1023) * 256 + threadIdx.x;   // over 256K float4 per matrix
  const float* src = (w == 0) ? Wq : (w == 1) ? Wk : Wv;
  float4 v = ((const float4*)src)[i];
  u16x4 o;
  o[0] = f2h(v.x); o[1] = f2h(v.y); o[2] = f2h(v.z); o[3] = f2h(v.w);
  ((u16x4*)(B3 + (size_t)w * DIM * DIM))[i] = o;
}

// ---- merged projections (flat grid 768, XCD-swizzled, uniform NT=16)
__global__ __launch_bounds__(512) void proj256_kernel(const u16* __restrict__ emb16,
                                                      const u16* __restrict__ B3,
                                                      const float* __restrict__ bq,
                                                      const float* __restrict__ bk,
                                                      const float* __restrict__ bv,
                                                      u16* __restrict__ q16,
                                                      u16* __restrict__ k16,
                                                      u16* __restrict__ vT) {
  __shared__ __align__(16) u16 sm[65536];  // 128KB
  const int wg = xcd_swz(blockIdx.x, 768);
  const int lane = threadIdx.x & 63, wid = threadIdx.x >> 6;
  f32x4 acc[8][4] = {};
  if (wg < 512) {
    const int m0 = (wg >> 3) * 256;
    const int z = (wg >> 2) & 1;
    const int n0 = (wg & 3) * 256;
    gemm256_core(emb16 + (size_t)m0 * 1024, B3 + (size_t)z * DIM * DIM + (size_t)n0 * 1024,
                 16, 1024, 1024, sm, acc);
    const int rb = m0 + ((wid >> 2) << 7) + ((lane >> 4) << 2);
    const int cb = n0 + ((wid & 3) << 6) + (lane & 15);
    const float* bias = z ? bk : bq;
    u16* dst = z ? k16 : q16;
#pragma unroll
    for (int m = 0; m < 8; ++m)
#pragma unroll
      for (int n = 0; n < 4; ++n)
#pragma unroll
        for (int j = 0; j < 4; ++j) {
          int row = rb + m * 16 + j;
          int col = cb + n * 16;
          dst[(size_t)row * DIM + col] = f2h(acc[m][n][j] + bias[col]);
        }
  } else {
    const int r = wg - 512;
    const int m0 = (r & 3) * 256;   // over DIM (Wv bands, L2-resident)
    const int n0 = (r >> 2) * 256;  // over MROWS (emb streamed once)
    gemm256_core(B3 + (size_t)2 * DIM * DIM + (size_t)m0 * 1024, emb16 + (size_t)n0 * 1024,
                 16, 1024, 1024, sm, acc);
    const int rb = m0 + ((wid >> 2) << 7) + ((lane >> 4) << 2);
    const int cb = n0 + ((wid & 3) << 6) + (lane & 15);
#pragma unroll
    for (int m = 0; m < 8; ++m)
#pragma unroll
      for (int n = 0; n < 4; ++n)
#pragma unroll
        for (int j = 0; j < 4; ++j) {
          int d = rb + m * 16 + j;     // 0..1023
          int kg = cb + n * 16;        // 0..16383
          int bi = kg >> 11, s = kg & 2047;
          vT[((size_t)bi << 21) + ((size_t)d << 11) + s] = f2h(acc[m][n][j] + bv[d]);
        }
  }
}

// ---- scores: scH = fp16( q.k^T / 32 )
__global__ __launch_bounds__(512) void scores256_kernel(const u16* __restrict__ q16,
                                                        const u16* __restrict__ k16,
                                                        u16* __restrict__ scH) {
  __shared__ __align__(16) u16 sm[65536];
  const int wg = xcd_swz(blockIdx.x, 512);
  const int b = wg >> 6;
  const int m0 = ((wg >> 3) & 7) * 256;
  const int n0 = (wg & 7) * 256;
  f32x4 acc[8][4] = {};
  gemm256_core(q16 + ((size_t)b * SEQ + m0) * DIM, k16 + ((size_t)b * SEQ + n0) * DIM,
               16, DIM, DIM, sm, acc);
  const int lane = threadIdx.x & 63, wid = threadIdx.x >> 6;
  const int rb = m0 + ((wid >> 2) << 7) + ((lane >> 4) << 2);
  const int cb = n0 + ((wid & 3) << 6) + (lane & 15);
#pragma unroll
  for (int m = 0; m < 8; ++m)
#pragma unroll
    for (int n = 0; n < 4; ++n)
#pragma unroll
      for (int j = 0; j < 4; ++j) {
        size_t idx = ((size_t)b * SEQ + rb + m * 16 + j) * SEQ + (cb + n * 16);
        scH[idx] = f2h(acc[m][n][j] * 0.03125f);
      }
}

// ---- softmax: f = scH + mask/32 (fp32 math), probs fp16 written in place
__global__ __launch_bounds__(256) void softmax_kernel(u16* __restrict__ scH,
                                                      const float* __restrict__ mask) {
  __shared__ float red[8];
  const size_t row = blockIdx.x;
  u16* rowp = scH + row * SEQ;
  const float* mrow = mask + row * SEQ;
  const int tid = threadIdx.x;
  short8 raw = *(const short8*)(rowp + tid * 8);
  float4 m0 = ((const float4*)mrow)[2 * tid];
  float4 m1 = ((const float4*)mrow)[2 * tid + 1];
  float mk[8] = {m0.x, m0.y, m0.z, m0.w, m1.x, m1.y, m1.z, m1.w};
  float f[8];
#pragma unroll
  for (int j = 0; j < 8; ++j) f[j] = h2f((u16)raw[j]) + mk[j] * 0.03125f;
  float mx = f[0];
#pragma unroll
  for (int j = 1; j < 8; ++j) mx = fmaxf(mx, f[j]);
#pragma unroll
  for (int off = 1; off < 64; off <<= 1) mx = fmaxf(mx, __shfl_xor(mx, off));
  const int wid = tid >> 6, lane = tid & 63;
  if (lane == 0) red[wid] = mx;
  __syncthreads();
  mx = fmaxf(fmaxf(red[0], red[1]), fmaxf(red[2], red[3]));
  float e[8];
  float s = 0.f;
#pragma unroll
  for (int j = 0; j < 8; ++j) {
    e[j] = __expf(f[j] - mx);
    s += e[j];
  }
#pragma unroll
  for (int off = 1; off < 64; off <<= 1) s += __shfl_xor(s, off);
  if (lane == 0) red[4 + wid] = s;
  __syncthreads();
  s = (red[4] + red[5]) + (red[6] + red[7]);
  const float inv = 1.f / s;
  short8 o;
#pragma unroll
  for (int j = 0; j < 8; ++j) o[j] = (short)f2h(e[j] * inv);
  *(short8*)(rowp + tid * 8) = o;
}

// ---- PV: out = probs @ v^T
__global__ __launch_bounds__(512) void pv256_kernel(const u16* __restrict__ pr,
                                                    const u16* __restrict__ vt,
                                                    float* __restrict__ out) {
  __shared__ __align__(16) u16 sm[65536];
  const int wg = xcd_swz(blockIdx.x, 256);
  const int b = wg >> 5;
  const int m0 = ((wg >> 2) & 7) * 256;
  const int n0 = (wg & 3) * 256;
  f32x4 acc[8][4] = {};
  gemm256_core(pr + ((size_t)b * SEQ + m0) * SEQ, vt + ((size_t)b * DIM + n0) * SEQ,
               32, SEQ, SEQ, sm, acc);
  const int lane = threadIdx.x & 63, wid = threadIdx.x >> 6;
  const int rb = m0 + ((wid >> 2) << 7) + ((lane >> 4) << 2);
  const int cb = n0 + ((wid & 3) << 6) + (lane & 15);
#pragma unroll
  for (int m = 0; m < 8; ++m)
#pragma unroll
    for (int n = 0; n < 4; ++n)
#pragma unroll
      for (int j = 0; j < 4; ++j)
        out[((size_t)b * SEQ + rb + m * 16 + j) * DIM + (cb + n * 16)] = acc[m][n][j];
}

extern "C" void kernel_launch(void* const* d_in, const int* in_sizes, int n_in,
                              void* d_out, int out_size, void* d_ws, size_t ws_size,
                              hipStream_t stream) {
  const float* emb  = (const float*)d_in[0];
  const float* mask = (const float*)d_in[1];
  const float* Wq   = (const float*)d_in[2];
  const float* bq   = (const float*)d_in[3];
  const float* Wk   = (const float*)d_in[4];
  const float* bk   = (const float*)d_in[5];
  const float* Wv   = (const float*)d_in[6];
  const float* bv   = (const float*)d_in[7];
  float* out = (float*)d_out;

  const size_t M1 = 1024 * 1024;
  u16* scH   = (u16*)d_ws;                    // 32M u16 (64MB), fp16 logits->probs
  u16* emb16 = scH + 32 * M1;                 // 16M
  u16* B3  = emb16 + 16 * M1;                 // 3M (Wq|Wk|Wv fp16)
  u16* q16 = B3 + 3 * M1;                     // 16M
  u16* k16 = q16 + 16 * M1;                   // 16M
  u16* vT  = k16 + 16 * M1;                   // 16M  (83M u16 = 166MB)

  cvt_kernel<<<16384, 256, 0, stream>>>(emb, emb16, (int)(4 * M1));
  cvt_w3_kernel<<<3072, 256, 0, stream>>>(Wq, Wk, Wv, B3);

  proj256_kernel<<<768, 512, 0, stream>>>(emb16, B3, bq, bk, bv, q16, k16, vT);

  scores256_kernel<<<512, 512, 0, stream>>>(q16, k16, scH);
  softmax_kernel<<<MROWS, 256, 0, stream>>>(scH, mask);
  pv256_kernel<<<256, 512, 0, stream>>>((const u16*)scH, vT, out);
}